// Round 1
// 922.951 us; speedup vs baseline: 1.0603x; 1.0603x over previous
//
#include <hip/hip_runtime.h>
#include <math.h>

#define B_ 16
#define D_ 256
#define M_ 2048
#define N_ 2048
#define EPSF 1e-8f
#define AVAL (1.0f/2048.0f)   // a_i = 1/M = b_j = 1/N ; m = 1

typedef __bf16  bf16x8 __attribute__((ext_vector_type(8)));
typedef float   f32x4  __attribute__((ext_vector_type(4)));

__device__ __forceinline__ float wredsum(float x){
  #pragma unroll
  for (int off=32; off; off>>=1) x += __shfl_xor(x, off);
  return x;
}
__device__ __forceinline__ float wredmax(float x){
  #pragma unroll
  for (int off=32; off; off>>=1) x = fmaxf(x, __shfl_xor(x, off));
  return x;
}
__device__ __forceinline__ unsigned short f2bf(float x){
  unsigned int v = __float_as_uint(x);
  unsigned int r = (v + 0x7fffu + ((v>>16)&1u)) >> 16;   // RNE
  return (unsigned short)r;
}
__device__ __forceinline__ float bf2f(unsigned short u){ return __uint_as_float(((unsigned int)u)<<16); }
__device__ __forceinline__ float h2f(unsigned short h){
  _Float16 x; __builtin_memcpy(&x,&h,2); return (float)x;
}
__device__ __forceinline__ unsigned short f2h(float x){
  _Float16 h = (_Float16)x; unsigned short u; __builtin_memcpy(&u,&h,2); return u;
}

// async global->LDS, 16B per lane. LDS dest is wave-uniform base + lane*16;
// our per-lane dest pointers are constructed exactly that way.
__device__ __forceinline__ void gll16(const void* gsrc, void* ldst){
  __builtin_amdgcn_global_load_lds(
      (const __attribute__((address_space(1))) unsigned int*)gsrc,
      (__attribute__((address_space(3))) unsigned int*)(unsigned int)(unsigned long long)ldst,
      16, 0, 0);
}

// ===== convert: fp32 [b][d][m] -> split-bf16 hi/lo planes in 16B granules =====
// Plane layout: granule index (b*32 + g)*2048 + m holds bf16 of elements
// d = g*8 .. g*8+7 for column m.  Identical rounding math to the old in-gemm
// conversion (f2bf RNE hi, f2bf residual lo) -> bitwise-identical GEMM result.
__global__ __launch_bounds__(256) void convert_kernel(const float* __restrict__ se,
                                                      const float* __restrict__ te,
                                                      uint4* __restrict__ Ah, uint4* __restrict__ Al,
                                                      uint4* __restrict__ Bh, uint4* __restrict__ Bl)
{
  const int t  = threadIdx.x;
  const int mb = blockIdx.x;            // 0..7   (m chunk of 256)
  const int g  = blockIdx.y;            // 0..31  (k-octet)
  const int z  = blockIdx.z;            // 0..31: b = z&15, op = z>>4
  const int b  = z & 15, op = z >> 4;
  const int m  = mb*256 + t;
  const float* src = (op ? te : se) + (size_t)b*D_*M_ + (size_t)g*8*M_ + m;
  float x[8];
  #pragma unroll
  for (int j=0;j<8;j++) x[j] = src[(size_t)j*M_];
  unsigned int hw[4], lw[4];
  #pragma unroll
  for (int p=0;p<4;p++){
    float a0 = x[2*p], a1 = x[2*p+1];
    unsigned short h0 = f2bf(a0), h1 = f2bf(a1);
    unsigned short q0 = f2bf(a0 - bf2f(h0)), q1 = f2bf(a1 - bf2f(h1));
    hw[p] = (unsigned)h0 | ((unsigned)h1<<16);
    lw[p] = (unsigned)q0 | ((unsigned)q1<<16);
  }
  const size_t gi = (size_t)(b*32 + g)*2048 + m;
  uint4* Ph = op ? Bh : Ah;
  uint4* Pl = op ? Bl : Al;
  Ph[gi] = *(const uint4*)hw;
  Pl[gi] = *(const uint4*)lw;
}

// ===== fast GEMM: pre-converted planes + global_load_lds staging =====
// LDS layout per plane: granule (gq in 0..3, m in 0..127) at linear gq*128+m,
// 16B each (8 consecutive k as bf16) -- identical to the old kernel's layout,
// so fragment reads / MFMA / epilogue are unchanged.
__global__ __launch_bounds__(256) void gemm_fast(const uint4* __restrict__ Ah,
                                                 const uint4* __restrict__ Al,
                                                 const uint4* __restrict__ Bh,
                                                 const uint4* __restrict__ Bl,
                                                 float* __restrict__ S)
{
  __shared__ unsigned int sAh[2048], sAl[2048], sBh[2048], sBl[2048];
  const int b  = blockIdx.z;
  const int mb = blockIdx.y;
  const int nb = blockIdx.x;
  const int t    = threadIdx.x;
  const int wave = t >> 6, lane = t & 63;
  const int wy = wave >> 1, wx = wave & 1;
  const int quad = lane >> 4, l15 = lane & 15;

  f32x4 acc[4][4] = {};

  for (int kc=0; kc<8; kc++){
    __syncthreads();                       // prev ds_reads drained (lgkmcnt by compiler)
    #pragma unroll
    for (int r=0;r<2;r++){
      const int i  = r*256 + t;            // linear granule 0..511
      const int gq = i >> 7, m = i & 127;
      const size_t rowg = (size_t)(b*32 + kc*4 + gq)*2048;
      gll16(Ah + rowg + mb*128 + m, (char*)sAh + (size_t)i*16);
      gll16(Al + rowg + mb*128 + m, (char*)sAl + (size_t)i*16);
      gll16(Bh + rowg + nb*128 + m, (char*)sBh + (size_t)i*16);
      gll16(Bl + rowg + nb*128 + m, (char*)sBl + (size_t)i*16);
    }
    __syncthreads();                       // vmcnt(0) drain by compiler -> LDS ready
    bf16x8 ah[4], al[4], bh[4], bl[4];
    #pragma unroll
    for (int rt=0;rt<4;rt++){
      int ra = (quad*128 + wy*64 + rt*16 + l15)*4;
      int rb = (quad*128 + wx*64 + rt*16 + l15)*4;
      ah[rt] = *(const bf16x8*)&sAh[ra];
      al[rt] = *(const bf16x8*)&sAl[ra];
      bh[rt] = *(const bf16x8*)&sBh[rb];
      bl[rt] = *(const bf16x8*)&sBl[rb];
    }
    #pragma unroll
    for (int rt=0;rt<4;rt++)
      #pragma unroll
      for (int ct=0;ct<4;ct++){
        acc[rt][ct] = __builtin_amdgcn_mfma_f32_16x16x32_bf16(ah[rt], bh[ct], acc[rt][ct], 0,0,0);
        acc[rt][ct] = __builtin_amdgcn_mfma_f32_16x16x32_bf16(ah[rt], bl[ct], acc[rt][ct], 0,0,0);
        acc[rt][ct] = __builtin_amdgcn_mfma_f32_16x16x32_bf16(al[rt], bh[ct], acc[rt][ct], 0,0,0);
      }
  }
  const float sc = 0.0625f;   // 1/sqrt(256)
  #pragma unroll
  for (int rt=0;rt<4;rt++){
    #pragma unroll
    for (int r=0;r<4;r++){
      int m = mb*128 + wy*64 + rt*16 + quad*4 + r;
      float* rowp = S + (size_t)(b*M_ + m)*N_;
      #pragma unroll
      for (int ct=0;ct<4;ct++){
        int n = nb*128 + wx*64 + ct*16 + l15;
        rowp[n] = acc[rt][ct][r] * sc;
      }
    }
  }
}

// ===== fallback GEMM (original, conversion inline) — used only if ws too small =====
__global__ __launch_bounds__(256) void gemm_kernel(const float* __restrict__ se,
                                                   const float* __restrict__ te,
                                                   float* __restrict__ S)
{
  __shared__ unsigned int Ah[2048], Al[2048], Bh[2048], Bl[2048];
  const int b  = blockIdx.z;
  const int mb = blockIdx.y;
  const int nb = blockIdx.x;
  const int t    = threadIdx.x;
  const int wave = t >> 6, lane = t & 63;
  const int wy = wave >> 1, wx = wave & 1;
  const int quad = lane >> 4, l15 = lane & 15;
  const int ml  = t & 127;
  const int dh  = t >> 7;

  f32x4 acc[4][4] = {};

  const float* Abase = se + (size_t)b*D_*M_ + mb*128 + ml;
  const float* Bbase = te + (size_t)b*D_*M_ + nb*128 + ml;

  for (int kc=0; kc<8; kc++){
    __syncthreads();
    {
      float x[16];
      #pragma unroll
      for (int j=0;j<16;j++) x[j] = Abase[(size_t)(kc*32 + dh*16 + j)*M_];
      #pragma unroll
      for (int gi=0; gi<2; gi++){
        unsigned int hw[4], lw[4];
        #pragma unroll
        for (int p=0;p<4;p++){
          float a0 = x[gi*8+2*p], a1 = x[gi*8+2*p+1];
          unsigned short h0 = f2bf(a0), h1 = f2bf(a1);
          unsigned short q0 = f2bf(a0 - bf2f(h0)), q1 = f2bf(a1 - bf2f(h1));
          hw[p] = (unsigned)h0 | ((unsigned)h1<<16);
          lw[p] = (unsigned)q0 | ((unsigned)q1<<16);
        }
        int idx = ((dh*2+gi)*128 + ml)*4;
        *(uint4*)&Ah[idx] = *(uint4*)hw;
        *(uint4*)&Al[idx] = *(uint4*)lw;
      }
    }
    {
      float x[16];
      #pragma unroll
      for (int j=0;j<16;j++) x[j] = Bbase[(size_t)(kc*32 + dh*16 + j)*M_];
      #pragma unroll
      for (int gi=0; gi<2; gi++){
        unsigned int hw[4], lw[4];
        #pragma unroll
        for (int p=0;p<4;p++){
          float a0 = x[gi*8+2*p], a1 = x[gi*8+2*p+1];
          unsigned short h0 = f2bf(a0), h1 = f2bf(a1);
          unsigned short q0 = f2bf(a0 - bf2f(h0)), q1 = f2bf(a1 - bf2f(h1));
          hw[p] = (unsigned)h0 | ((unsigned)h1<<16);
          lw[p] = (unsigned)q0 | ((unsigned)q1<<16);
        }
        int idx = ((dh*2+gi)*128 + ml)*4;
        *(uint4*)&Bh[idx] = *(uint4*)hw;
        *(uint4*)&Bl[idx] = *(uint4*)lw;
      }
    }
    __syncthreads();
    bf16x8 ah[4], al[4], bh[4], bl[4];
    #pragma unroll
    for (int rt=0;rt<4;rt++){
      int ra = (quad*128 + wy*64 + rt*16 + l15)*4;
      int rb = (quad*128 + wx*64 + rt*16 + l15)*4;
      ah[rt] = *(const bf16x8*)&Ah[ra];
      al[rt] = *(const bf16x8*)&Al[ra];
      bh[rt] = *(const bf16x8*)&Bh[rb];
      bl[rt] = *(const bf16x8*)&Bl[rb];
    }
    #pragma unroll
    for (int rt=0;rt<4;rt++)
      #pragma unroll
      for (int ct=0;ct<4;ct++){
        acc[rt][ct] = __builtin_amdgcn_mfma_f32_16x16x32_bf16(ah[rt], bh[ct], acc[rt][ct], 0,0,0);
        acc[rt][ct] = __builtin_amdgcn_mfma_f32_16x16x32_bf16(ah[rt], bl[ct], acc[rt][ct], 0,0,0);
        acc[rt][ct] = __builtin_amdgcn_mfma_f32_16x16x32_bf16(al[rt], bh[ct], acc[rt][ct], 0,0,0);
      }
  }
  const float sc = 0.0625f;
  #pragma unroll
  for (int rt=0;rt<4;rt++){
    #pragma unroll
    for (int r=0;r<4;r++){
      int m = mb*128 + wy*64 + rt*16 + quad*4 + r;
      float* rowp = S + (size_t)(b*M_ + m)*N_;
      #pragma unroll
      for (int ct=0;ct<4;ct++){
        int n = nb*128 + wx*64 + ct*16 + l15;
        rowp[n] = acc[rt][ct][r] * sc;
      }
    }
  }
}

// ===== stats: per-row lse; K̂=exp((s-lse)/rho) stored fp16 in-place (front 4KB);
//       y0 = sum of the STORED fp16 K̂ (consistency with later passes) =====
__global__ __launch_bounds__(256) void stats_kernel(float* __restrict__ S,
                                                    const float* __restrict__ rho,
                                                    float* __restrict__ lse,
                                                    float* __restrict__ y0)
{
  const int b = blockIdx.y;
  const int m = blockIdx.x*4 + (threadIdx.x>>6);
  const int lane = threadIdx.x & 63;
  const float invrho = 1.0f / fmaxf(rho[0], EPSF);
  float* row = S + (size_t)(b*M_ + m)*N_;
  const float4* row4 = (const float4*)row;
  float4 vals[8];
  float mx = -3.4e38f;
  #pragma unroll
  for (int k=0;k<8;k++){
    float4 v = row4[lane + 64*k];
    vals[k] = v;
    mx = fmaxf(mx, fmaxf(fmaxf(v.x,v.y), fmaxf(v.z,v.w)));
  }
  mx = wredmax(mx);
  float e1=0.0f;
  #pragma unroll
  for (int k=0;k<8;k++){
    float4 v = vals[k];
    e1 += __expf(v.x-mx)+__expf(v.y-mx)+__expf(v.z-mx)+__expf(v.w-mx);
  }
  e1 = wredsum(e1);
  const float l = mx + __logf(e1);
  uint2* rowh2 = (uint2*)row;
  float y2 = 0.0f;
  #pragma unroll
  for (int k=0;k<8;k++){
    float4 v = vals[k];
    unsigned short h0 = f2h(__expf((v.x-l)*invrho));
    unsigned short h1 = f2h(__expf((v.y-l)*invrho));
    unsigned short h2 = f2h(__expf((v.z-l)*invrho));
    unsigned short h3 = f2h(__expf((v.w-l)*invrho));
    y2 += h2f(h0)+h2f(h1)+h2f(h2)+h2f(h3);
    uint2 pk;
    pk.x = (unsigned)h0 | ((unsigned)h1<<16);
    pk.y = (unsigned)h2 | ((unsigned)h3<<16);
    rowh2[lane + 64*k] = pk;
  }
  y2 = wredsum(y2);
  if (lane==0){
    lse[b*M_+m] = l;
    y0 [b*M_+m] = y2;
  }
}

__global__ __launch_bounds__(256) void init_kernel(const float* __restrict__ y0,
                                                   float* __restrict__ u, float* __restrict__ v,
                                                   float* __restrict__ w, float* __restrict__ g)
{
  const int b = blockIdx.x; const int t = threadIdx.x;
  float s = 0.0f;
  for (int i=t;i<M_;i+=256) s += y0[b*M_+i];
  s = wredsum(s);
  __shared__ float red[4];
  __shared__ float gsh;
  if ((t&63)==0) red[t>>6]=s;
  __syncthreads();
  if (t==0){
    float tot = red[0]+red[1]+red[2]+red[3];
    float gg = 1.0f / fmaxf(tot, EPSF);
    g[b]=gg; gsh=gg;
  }
  __syncthreads();
  float gg = gsh;
  for (int i=t;i<M_;i+=256){
    float rs = gg * y0[b*M_+i];
    u[b*M_+i] = fminf(AVAL / fmaxf(rs, EPSF), 1.0f);
    v[b*M_+i] = 1.0f;
    w[b*M_+i] = 0.0f;
  }
}

// ---- row pass: u_i *= min(a/max(g u_i (K̂ v)_i,eps),1); K̂ read as fp16, no exp ----
__global__ __launch_bounds__(256) void row_kernel(const float* __restrict__ S,
                                                  const float* __restrict__ vv,
                                                  float* __restrict__ u,
                                                  const float* __restrict__ g)
{
  const int b = blockIdx.y;
  const int m = blockIdx.x*4 + (threadIdx.x>>6);
  const int lane = threadIdx.x & 63;
  const uint4*  rowh = (const uint4*)(S + (size_t)(b*M_ + m)*N_);
  const float4* vp   = (const float4*)(vv + (size_t)b*N_);
  float acc=0.0f;
  #pragma unroll
  for (int k=0;k<4;k++){
    uint4 su = rowh[lane + 64*k];
    float4 v0 = vp[(lane+64*k)*2];
    float4 v1 = vp[(lane+64*k)*2+1];
    acc += h2f((unsigned short)(su.x&0xffff))*v0.x + h2f((unsigned short)(su.x>>16))*v0.y
         + h2f((unsigned short)(su.y&0xffff))*v0.z + h2f((unsigned short)(su.y>>16))*v0.w
         + h2f((unsigned short)(su.z&0xffff))*v1.x + h2f((unsigned short)(su.z>>16))*v1.y
         + h2f((unsigned short)(su.w&0xffff))*v1.z + h2f((unsigned short)(su.w>>16))*v1.w;
  }
  acc = wredsum(acc);
  if (lane==0){
    float ui = u[b*M_+m];
    float rs = g[b]*ui*acc;
    u[b*M_+m] = ui * fminf(AVAL / fmaxf(rs, EPSF), 1.0f);
  }
}

// ---- col pass: w_j += sum_i u_i K̂_ij over 64-row chunks ----
__global__ __launch_bounds__(256) void col_kernel(const float* __restrict__ S,
                                                  const float* __restrict__ u,
                                                  float* __restrict__ w)
{
  const int b  = blockIdx.y;
  const int i0 = blockIdx.x*64;
  const int t  = threadIdx.x;
  float acc[8];
  #pragma unroll
  for (int k=0;k<8;k++) acc[k]=0.0f;
  for (int i=0;i<64;i++){
    int r = i0+i;
    float ui = u[b*M_+r];
    uint4 su = ((const uint4*)(S + (size_t)(b*M_ + r)*N_))[t];
    acc[0] += ui*h2f((unsigned short)(su.x&0xffff));
    acc[1] += ui*h2f((unsigned short)(su.x>>16));
    acc[2] += ui*h2f((unsigned short)(su.y&0xffff));
    acc[3] += ui*h2f((unsigned short)(su.y>>16));
    acc[4] += ui*h2f((unsigned short)(su.z&0xffff));
    acc[5] += ui*h2f((unsigned short)(su.z>>16));
    acc[6] += ui*h2f((unsigned short)(su.w&0xffff));
    acc[7] += ui*h2f((unsigned short)(su.w>>16));
  }
  #pragma unroll
  for (int k=0;k<8;k++) atomicAdd(&w[b*N_+t*8+k], acc[k]);
}

__global__ __launch_bounds__(256) void vupd_kernel(float* __restrict__ w,
                                                   float* __restrict__ v,
                                                   float* __restrict__ g)
{
  const int b = blockIdx.x; const int t = threadIdx.x;
  const float gg = g[b];
  float part = 0.0f;
  for (int i=t;i<N_;i+=256){
    float wj = w[b*N_+i];
    float vj = v[b*N_+i];
    float c  = fminf(AVAL/fmaxf(gg*vj*wj,EPSF), 1.0f);
    vj *= c;
    v[b*N_+i]=vj;
    part += wj*vj;
    w[b*N_+i]=0.0f;
  }
  part = wredsum(part);
  __shared__ float red[4];
  if ((t&63)==0) red[t>>6]=part;
  __syncthreads();
  if (t==0){
    float tot = gg*(red[0]+red[1]+red[2]+red[3]);
    g[b] = gg / fmaxf(tot, EPSF);
  }
}

// ---- final: matches fp32 overwrite rows in place; fused rowsum + matches@t^T ----
__global__ __launch_bounds__(256) void final_kernel(float* __restrict__ S,
                                                    const float* __restrict__ u,
                                                    const float* __restrict__ v,
                                                    const float* __restrict__ g,
                                                    const float* __restrict__ tgt,
                                                    float* __restrict__ rowsum,
                                                    float* __restrict__ wref)
{
  const int b = blockIdx.y;
  const int m = blockIdx.x*4 + (threadIdx.x>>6);
  const int lane = threadIdx.x & 63;
  const float gu = g[b]*u[b*M_+m];
  float* row = S + (size_t)(b*M_ + m)*N_;
  const uint4* rowh = (const uint4*)row;
  uint4 su[4];
  #pragma unroll
  for (int k=0;k<4;k++) su[k] = rowh[lane + 64*k];
  __builtin_amdgcn_s_waitcnt(0);
  float4* rowf = (float4*)row;
  const float4* vp = (const float4*)(v + (size_t)b*N_);
  const float4* t0 = (const float4*)(tgt + ((size_t)b*3+0)*N_);
  const float4* t1 = (const float4*)(tgt + ((size_t)b*3+1)*N_);
  const float4* t2 = (const float4*)(tgt + ((size_t)b*3+2)*N_);
  float rs=0.0f, a0=0.0f, a1=0.0f, a2=0.0f;
  #pragma unroll
  for (int k=0;k<4;k++){
    float s[8] = {h2f((unsigned short)(su[k].x&0xffff)), h2f((unsigned short)(su[k].x>>16)),
                  h2f((unsigned short)(su[k].y&0xffff)), h2f((unsigned short)(su[k].y>>16)),
                  h2f((unsigned short)(su[k].z&0xffff)), h2f((unsigned short)(su[k].z>>16)),
                  h2f((unsigned short)(su[k].w&0xffff)), h2f((unsigned short)(su[k].w>>16))};
    int i2 = (lane+64*k)*2;
    #pragma unroll
    for (int h=0;h<2;h++){
      float4 v4 = vp[i2+h];
      float4 q0 = t0[i2+h], q1 = t1[i2+h], q2 = t2[i2+h];
      float m0 = gu*s[h*4+0]*v4.x;
      float m1 = gu*s[h*4+1]*v4.y;
      float m2 = gu*s[h*4+2]*v4.z;
      float m3 = gu*s[h*4+3]*v4.w;
      rs += m0+m1+m2+m3;
      a0 += m0*q0.x + m1*q0.y + m2*q0.z + m3*q0.w;
      a1 += m0*q1.x + m1*q1.y + m2*q1.z + m3*q1.w;
      a2 += m0*q2.x + m1*q2.y + m2*q2.z + m3*q2.w;
      rowf[i2+h] = make_float4(m0,m1,m2,m3);
    }
  }
  rs = wredsum(rs); a0=wredsum(a0); a1=wredsum(a1); a2=wredsum(a2);
  if (lane==0){
    rowsum[b*M_+m] = rs;
    float inv = 1.0f/(rs+1e-6f);
    size_t o = ((size_t)b*M_+m)*3;
    wref[o]=a0*inv; wref[o+1]=a1*inv; wref[o+2]=a2*inv;
  }
}

// ---------------- 3x3 Kabsch via Jacobi on cov^T cov (verified R1) ----------------
__device__ __forceinline__ void mat3_svd_rot(const float cov[3][3], float R[3][3])
{
  float mx = 1e-30f;
  for (int p=0;p<3;p++) for (int q=0;q<3;q++) mx = fmaxf(mx, fabsf(cov[p][q]));
  const float inv = 1.0f/mx;
  float Cm[3][3];
  for (int p=0;p<3;p++) for (int q=0;q<3;q++) Cm[p][q]=cov[p][q]*inv;
  float G[3][3];
  for (int p=0;p<3;p++)
    for (int q=0;q<3;q++)
      G[p][q] = Cm[0][p]*Cm[0][q] + Cm[1][p]*Cm[1][q] + Cm[2][p]*Cm[2][q];
  float V[3][3] = {{1,0,0},{0,1,0},{0,0,1}};
  const int PP[3]={0,0,1}, QQ[3]={1,2,2};
  for (int sweep=0;sweep<12;sweep++){
    for (int r=0;r<3;r++){
      int p=PP[r], q=QQ[r];
      float apq = G[p][q];
      if (fabsf(apq) < 1e-20f) continue;
      float tau = (G[q][q]-G[p][p])/(2.0f*apq);
      float tt  = (tau>=0.0f?1.0f:-1.0f)/(fabsf(tau)+sqrtf(1.0f+tau*tau));
      float cc  = 1.0f/sqrtf(1.0f+tt*tt);
      float ss  = tt*cc;
      for (int k=0;k<3;k++){ float gkp=G[k][p], gkq=G[k][q]; G[k][p]=cc*gkp-ss*gkq; G[k][q]=ss*gkp+cc*gkq; }
      for (int k=0;k<3;k++){ float gpk=G[p][k], gqk=G[q][k]; G[p][k]=cc*gpk-ss*gqk; G[q][k]=ss*gpk+cc*gqk; }
      for (int k=0;k<3;k++){ float vkp=V[k][p], vkq=V[k][q]; V[k][p]=cc*vkp-ss*vkq; V[k][q]=ss*vkp+cc*vkq; }
    }
  }
  float ev[3]={G[0][0],G[1][1],G[2][2]};
  int i0=0,i1=1,i2=2,tmp;
  if (ev[i0]<ev[i1]){tmp=i0;i0=i1;i1=tmp;}
  if (ev[i0]<ev[i2]){tmp=i0;i0=i2;i2=tmp;}
  if (ev[i1]<ev[i2]){tmp=i1;i1=i2;i2=tmp;}
  const int idx[3]={i0,i1,i2};
  float Vs[3][3];
  for (int k=0;k<3;k++) for (int i=0;i<3;i++) Vs[i][k]=V[i][idx[k]];
  float U[3][3]; float nrm[3];
  for (int k=0;k<3;k++){
    float ux = Cm[0][0]*Vs[0][k]+Cm[0][1]*Vs[1][k]+Cm[0][2]*Vs[2][k];
    float uy = Cm[1][0]*Vs[0][k]+Cm[1][1]*Vs[1][k]+Cm[1][2]*Vs[2][k];
    float uz = Cm[2][0]*Vs[0][k]+Cm[2][1]*Vs[1][k]+Cm[2][2]*Vs[2][k];
    float n = sqrtf(ux*ux+uy*uy+uz*uz);
    nrm[k]=n;
    float in = (n>1e-20f)?1.0f/n:0.0f;
    U[0][k]=ux*in; U[1][k]=uy*in; U[2][k]=uz*in;
  }
  if (nrm[2] < 1e-6f*fmaxf(nrm[0],1e-20f)){
    U[0][2]=U[1][0]*U[2][1]-U[2][0]*U[1][1];
    U[1][2]=U[2][0]*U[0][1]-U[0][0]*U[2][1];
    U[2][2]=U[0][0]*U[1][1]-U[1][0]*U[0][1];
  }
  float detC = Cm[0][0]*(Cm[1][1]*Cm[2][2]-Cm[1][2]*Cm[2][1])
             - Cm[0][1]*(Cm[1][0]*Cm[2][2]-Cm[1][2]*Cm[2][0])
             + Cm[0][2]*(Cm[1][0]*Cm[2][1]-Cm[1][1]*Cm[2][0]);
  float d2 = (detC>0.0f)?1.0f:-1.0f;
  for (int p=0;p<3;p++)
    for (int q=0;q<3;q++)
      R[p][q] = Vs[p][0]*U[q][0] + Vs[p][1]*U[q][1] + d2*Vs[p][2]*U[q][2];
}

__global__ __launch_bounds__(256) void rigid_kernel(const float* __restrict__ src,
                                                    const float* __restrict__ wref,
                                                    const float* __restrict__ rowsum,
                                                    float* __restrict__ out)
{
  const int b = blockIdx.x; const int t = threadIdx.x;
  float acc[16];
  #pragma unroll
  for (int k=0;k<16;k++) acc[k]=0.0f;
  for (int i=t;i<M_;i+=256){
    float wgt = rowsum[b*M_+i];
    float ax = src[((size_t)b*3+0)*M_+i];
    float ay = src[((size_t)b*3+1)*M_+i];
    float az = src[((size_t)b*3+2)*M_+i];
    const float* wr = wref + ((size_t)b*M_+i)*3;
    float bx=wr[0], by=wr[1], bz=wr[2];
    acc[0]+=wgt;
    acc[1]+=wgt*ax; acc[2]+=wgt*ay; acc[3]+=wgt*az;
    acc[4]+=wgt*bx; acc[5]+=wgt*by; acc[6]+=wgt*bz;
    acc[7] +=wgt*ax*bx; acc[8] +=wgt*ax*by; acc[9] +=wgt*ax*bz;
    acc[10]+=wgt*ay*bx; acc[11]+=wgt*ay*by; acc[12]+=wgt*ay*bz;
    acc[13]+=wgt*az*bx; acc[14]+=wgt*az*by; acc[15]+=wgt*az*bz;
  }
  __shared__ float red[4][16];
  const int wid = t>>6, lane = t&63;
  #pragma unroll
  for (int k=0;k<16;k++){
    float v = acc[k];
    #pragma unroll
    for (int off=32; off; off>>=1) v += __shfl_xor(v, off);
    if (lane==0) red[wid][k]=v;
  }
  __syncthreads();
  if (t==0){
    float s[16];
    #pragma unroll
    for (int k=0;k<16;k++) s[k]=red[0][k]+red[1][k]+red[2][k]+red[3][k];
    float wsum = s[0];
    float denom = wsum + 1e-6f;
    float ca[3]={s[1]/denom, s[2]/denom, s[3]/denom};
    float cb[3]={s[4]/denom, s[5]/denom, s[6]/denom};
    float sw = wsum/denom;
    float cov[3][3];
    for (int p=0;p<3;p++)
      for (int q=0;q<3;q++)
        cov[p][q] = s[7+p*3+q]/denom + (sw-2.0f)*ca[p]*cb[q];
    float R[3][3];
    mat3_svd_rot(cov, R);
    float tr[3];
    for (int p=0;p<3;p++)
      tr[p] = -(R[p][0]*ca[0]+R[p][1]*ca[1]+R[p][2]*ca[2]) + cb[p];
    for (int p=0;p<3;p++)
      for (int q=0;q<3;q++)
        out[b*9 + p*3 + q] = R[p][q];
    for (int p=0;p<3;p++)
      out[144 + b*3 + p] = tr[p];
  }
}

extern "C" void kernel_launch(void* const* d_in, const int* in_sizes, int n_in,
                              void* d_out, int out_size, void* d_ws, size_t ws_size,
                              hipStream_t stream)
{
  const float* se  = (const float*)d_in[0];
  const float* te  = (const float*)d_in[1];
  const float* src = (const float*)d_in[2];
  const float* tgt = (const float*)d_in[3];
  const float* rho = (const float*)d_in[4];
  float* out = (float*)d_out;
  float* S   = out + 192;                 // matches region doubles as S / K̂ scratch
  float* ws  = (float*)d_ws;
  float* lse = ws;                        // 16*2048
  float* y0  = ws + 32768;                // 16*2048 (also final rowsum)
  float* u   = ws + 65536;
  float* v   = ws + 98304;
  float* w   = ws + 131072;
  float* g   = ws + 163840;               // 16
  float* wref= ws + 163904;               // 16*2048*3 -> ends at float 262208 (byte 1048832)

  // split-bf16 operand planes (behind the existing ws layout)
  const size_t PLANE_G     = (size_t)16*32*2048;          // granules per plane
  const size_t PLANE_BYTES = PLANE_G*16;                  // 16.78 MB
  const size_t PLANE_OFF   = 1048832;                     // 16B-aligned
  const size_t need        = PLANE_OFF + 4*PLANE_BYTES;   // ~68.2 MB

  if (ws_size >= need){
    uint4* Ah = (uint4*)((char*)d_ws + PLANE_OFF);
    uint4* Al = Ah + PLANE_G;
    uint4* Bh = Al + PLANE_G;
    uint4* Bl = Bh + PLANE_G;
    convert_kernel<<<dim3(8,32,32),256,0,stream>>>(se,te,Ah,Al,Bh,Bl);
    gemm_fast     <<<dim3(16,16,16),256,0,stream>>>(Ah,Al,Bh,Bl,S);
  } else {
    gemm_kernel   <<<dim3(16,16,16),256,0,stream>>>(se,te,S);
  }
  stats_kernel<<<dim3(512,16),  256,0,stream>>>(S,rho,lse,y0);
  init_kernel <<<dim3(16),      256,0,stream>>>(y0,u,v,w,g);
  for (int it=0; it<5; ++it){
    if (it>0) row_kernel<<<dim3(512,16),256,0,stream>>>(S,v,u,g);
    col_kernel <<<dim3(32,16),256,0,stream>>>(S,u,w);
    vupd_kernel<<<dim3(16),   256,0,stream>>>(w,v,g);
  }
  final_kernel<<<dim3(512,16),256,0,stream>>>(S,u,v,g,tgt,y0,wref);
  rigid_kernel<<<dim3(16),    256,0,stream>>>(src,wref,y0,out);
}

// Round 2
// 835.412 us; speedup vs baseline: 1.1714x; 1.1048x over previous
//
#include <hip/hip_runtime.h>
#include <math.h>

#define B_ 16
#define D_ 256
#define M_ 2048
#define N_ 2048
#define EPSF 1e-8f
#define AVAL (1.0f/2048.0f)   // a_i = 1/M = b_j = 1/N ; m = 1

typedef __bf16  bf16x8 __attribute__((ext_vector_type(8)));
typedef float   f32x4  __attribute__((ext_vector_type(4)));

__device__ __forceinline__ float wredsum(float x){
  #pragma unroll
  for (int off=32; off; off>>=1) x += __shfl_xor(x, off);
  return x;
}
__device__ __forceinline__ float wredmax(float x){
  #pragma unroll
  for (int off=32; off; off>>=1) x = fmaxf(x, __shfl_xor(x, off));
  return x;
}
__device__ __forceinline__ unsigned short f2bf(float x){
  unsigned int v = __float_as_uint(x);
  unsigned int r = (v + 0x7fffu + ((v>>16)&1u)) >> 16;   // RNE
  return (unsigned short)r;
}
__device__ __forceinline__ float bf2f(unsigned short u){ return __uint_as_float(((unsigned int)u)<<16); }
__device__ __forceinline__ float h2f(unsigned short h){
  _Float16 x; __builtin_memcpy(&x,&h,2); return (float)x;
}
__device__ __forceinline__ unsigned short f2h(float x){
  _Float16 h = (_Float16)x; unsigned short u; __builtin_memcpy(&u,&h,2); return u;
}

// async global->LDS, 16B per lane. LDS dest is wave-uniform base + lane*16;
// our per-lane dest pointers are constructed exactly that way.
__device__ __forceinline__ void gll16(const void* gsrc, void* ldst){
  __builtin_amdgcn_global_load_lds(
      (const __attribute__((address_space(1))) unsigned int*)gsrc,
      (__attribute__((address_space(3))) unsigned int*)(unsigned int)(unsigned long long)ldst,
      16, 0, 0);
}

// ===== convert: fp32 [b][d][m] -> split-bf16 hi/lo planes in 16B granules =====
__global__ __launch_bounds__(256) void convert_kernel(const float* __restrict__ se,
                                                      const float* __restrict__ te,
                                                      uint4* __restrict__ Ah, uint4* __restrict__ Al,
                                                      uint4* __restrict__ Bh, uint4* __restrict__ Bl)
{
  const int t  = threadIdx.x;
  const int mb = blockIdx.x;            // 0..7   (m chunk of 256)
  const int g  = blockIdx.y;            // 0..31  (k-octet)
  const int z  = blockIdx.z;            // 0..31: b = z&15, op = z>>4
  const int b  = z & 15, op = z >> 4;
  const int m  = mb*256 + t;
  const float* src = (op ? te : se) + (size_t)b*D_*M_ + (size_t)g*8*M_ + m;
  float x[8];
  #pragma unroll
  for (int j=0;j<8;j++) x[j] = src[(size_t)j*M_];
  unsigned int hw[4], lw[4];
  #pragma unroll
  for (int p=0;p<4;p++){
    float a0 = x[2*p], a1 = x[2*p+1];
    unsigned short h0 = f2bf(a0), h1 = f2bf(a1);
    unsigned short q0 = f2bf(a0 - bf2f(h0)), q1 = f2bf(a1 - bf2f(h1));
    hw[p] = (unsigned)h0 | ((unsigned)h1<<16);
    lw[p] = (unsigned)q0 | ((unsigned)q1<<16);
  }
  const size_t gi = (size_t)(b*32 + g)*2048 + m;
  uint4* Ph = op ? Bh : Ah;
  uint4* Pl = op ? Bl : Al;
  Ph[gi] = *(const uint4*)hw;
  Pl[gi] = *(const uint4*)lw;
}

// ===== fast GEMM: pre-converted planes + global_load_lds staging =====
__global__ __launch_bounds__(256) void gemm_fast(const uint4* __restrict__ Ah,
                                                 const uint4* __restrict__ Al,
                                                 const uint4* __restrict__ Bh,
                                                 const uint4* __restrict__ Bl,
                                                 float* __restrict__ S)
{
  __shared__ unsigned int sAh[2048], sAl[2048], sBh[2048], sBl[2048];
  const int b  = blockIdx.z;
  const int mb = blockIdx.y;
  const int nb = blockIdx.x;
  const int t    = threadIdx.x;
  const int wave = t >> 6, lane = t & 63;
  const int wy = wave >> 1, wx = wave & 1;
  const int quad = lane >> 4, l15 = lane & 15;

  f32x4 acc[4][4] = {};

  for (int kc=0; kc<8; kc++){
    __syncthreads();                       // prev ds_reads drained (lgkmcnt by compiler)
    #pragma unroll
    for (int r=0;r<2;r++){
      const int i  = r*256 + t;            // linear granule 0..511
      const int gq = i >> 7, m = i & 127;
      const size_t rowg = (size_t)(b*32 + kc*4 + gq)*2048;
      gll16(Ah + rowg + mb*128 + m, (char*)sAh + (size_t)i*16);
      gll16(Al + rowg + mb*128 + m, (char*)sAl + (size_t)i*16);
      gll16(Bh + rowg + nb*128 + m, (char*)sBh + (size_t)i*16);
      gll16(Bl + rowg + nb*128 + m, (char*)sBl + (size_t)i*16);
    }
    __syncthreads();                       // vmcnt(0) drain by compiler -> LDS ready
    bf16x8 ah[4], al[4], bh[4], bl[4];
    #pragma unroll
    for (int rt=0;rt<4;rt++){
      int ra = (quad*128 + wy*64 + rt*16 + l15)*4;
      int rb = (quad*128 + wx*64 + rt*16 + l15)*4;
      ah[rt] = *(const bf16x8*)&sAh[ra];
      al[rt] = *(const bf16x8*)&sAl[ra];
      bh[rt] = *(const bf16x8*)&sBh[rb];
      bl[rt] = *(const bf16x8*)&sBl[rb];
    }
    #pragma unroll
    for (int rt=0;rt<4;rt++)
      #pragma unroll
      for (int ct=0;ct<4;ct++){
        acc[rt][ct] = __builtin_amdgcn_mfma_f32_16x16x32_bf16(ah[rt], bh[ct], acc[rt][ct], 0,0,0);
        acc[rt][ct] = __builtin_amdgcn_mfma_f32_16x16x32_bf16(ah[rt], bl[ct], acc[rt][ct], 0,0,0);
        acc[rt][ct] = __builtin_amdgcn_mfma_f32_16x16x32_bf16(al[rt], bh[ct], acc[rt][ct], 0,0,0);
      }
  }
  const float sc = 0.0625f;   // 1/sqrt(256)
  #pragma unroll
  for (int rt=0;rt<4;rt++){
    #pragma unroll
    for (int r=0;r<4;r++){
      int m = mb*128 + wy*64 + rt*16 + quad*4 + r;
      float* rowp = S + (size_t)(b*M_ + m)*N_;
      #pragma unroll
      for (int ct=0;ct<4;ct++){
        int n = nb*128 + wx*64 + ct*16 + l15;
        rowp[n] = acc[rt][ct][r] * sc;
      }
    }
  }
}

// ===== fallback GEMM (original, conversion inline) — used only if ws too small =====
__global__ __launch_bounds__(256) void gemm_kernel(const float* __restrict__ se,
                                                   const float* __restrict__ te,
                                                   float* __restrict__ S)
{
  __shared__ unsigned int Ah[2048], Al[2048], Bh[2048], Bl[2048];
  const int b  = blockIdx.z;
  const int mb = blockIdx.y;
  const int nb = blockIdx.x;
  const int t    = threadIdx.x;
  const int wave = t >> 6, lane = t & 63;
  const int wy = wave >> 1, wx = wave & 1;
  const int quad = lane >> 4, l15 = lane & 15;
  const int ml  = t & 127;
  const int dh  = t >> 7;

  f32x4 acc[4][4] = {};

  const float* Abase = se + (size_t)b*D_*M_ + mb*128 + ml;
  const float* Bbase = te + (size_t)b*D_*M_ + nb*128 + ml;

  for (int kc=0; kc<8; kc++){
    __syncthreads();
    {
      float x[16];
      #pragma unroll
      for (int j=0;j<16;j++) x[j] = Abase[(size_t)(kc*32 + dh*16 + j)*M_];
      #pragma unroll
      for (int gi=0; gi<2; gi++){
        unsigned int hw[4], lw[4];
        #pragma unroll
        for (int p=0;p<4;p++){
          float a0 = x[gi*8+2*p], a1 = x[gi*8+2*p+1];
          unsigned short h0 = f2bf(a0), h1 = f2bf(a1);
          unsigned short q0 = f2bf(a0 - bf2f(h0)), q1 = f2bf(a1 - bf2f(h1));
          hw[p] = (unsigned)h0 | ((unsigned)h1<<16);
          lw[p] = (unsigned)q0 | ((unsigned)q1<<16);
        }
        int idx = ((dh*2+gi)*128 + ml)*4;
        *(uint4*)&Ah[idx] = *(uint4*)hw;
        *(uint4*)&Al[idx] = *(uint4*)lw;
      }
    }
    {
      float x[16];
      #pragma unroll
      for (int j=0;j<16;j++) x[j] = Bbase[(size_t)(kc*32 + dh*16 + j)*M_];
      #pragma unroll
      for (int gi=0; gi<2; gi++){
        unsigned int hw[4], lw[4];
        #pragma unroll
        for (int p=0;p<4;p++){
          float a0 = x[gi*8+2*p], a1 = x[gi*8+2*p+1];
          unsigned short h0 = f2bf(a0), h1 = f2bf(a1);
          unsigned short q0 = f2bf(a0 - bf2f(h0)), q1 = f2bf(a1 - bf2f(h1));
          hw[p] = (unsigned)h0 | ((unsigned)h1<<16);
          lw[p] = (unsigned)q0 | ((unsigned)q1<<16);
        }
        int idx = ((dh*2+gi)*128 + ml)*4;
        *(uint4*)&Bh[idx] = *(uint4*)hw;
        *(uint4*)&Bl[idx] = *(uint4*)lw;
      }
    }
    __syncthreads();
    bf16x8 ah[4], al[4], bh[4], bl[4];
    #pragma unroll
    for (int rt=0;rt<4;rt++){
      int ra = (quad*128 + wy*64 + rt*16 + l15)*4;
      int rb = (quad*128 + wx*64 + rt*16 + l15)*4;
      ah[rt] = *(const bf16x8*)&Ah[ra];
      al[rt] = *(const bf16x8*)&Al[ra];
      bh[rt] = *(const bf16x8*)&Bh[rb];
      bl[rt] = *(const bf16x8*)&Bl[rb];
    }
    #pragma unroll
    for (int rt=0;rt<4;rt++)
      #pragma unroll
      for (int ct=0;ct<4;ct++){
        acc[rt][ct] = __builtin_amdgcn_mfma_f32_16x16x32_bf16(ah[rt], bh[ct], acc[rt][ct], 0,0,0);
        acc[rt][ct] = __builtin_amdgcn_mfma_f32_16x16x32_bf16(ah[rt], bl[ct], acc[rt][ct], 0,0,0);
        acc[rt][ct] = __builtin_amdgcn_mfma_f32_16x16x32_bf16(al[rt], bh[ct], acc[rt][ct], 0,0,0);
      }
  }
  const float sc = 0.0625f;
  #pragma unroll
  for (int rt=0;rt<4;rt++){
    #pragma unroll
    for (int r=0;r<4;r++){
      int m = mb*128 + wy*64 + rt*16 + quad*4 + r;
      float* rowp = S + (size_t)(b*M_ + m)*N_;
      #pragma unroll
      for (int ct=0;ct<4;ct++){
        int n = nb*128 + wx*64 + ct*16 + l15;
        rowp[n] = acc[rt][ct][r] * sc;
      }
    }
  }
}

// ===== stats: per-row lse; K̂=exp((s-lse)/rho) stored fp16 in-place (front 4KB);
//       y0 = sum of the STORED fp16 K̂ (consistency with later passes) =====
__global__ __launch_bounds__(256) void stats_kernel(float* __restrict__ S,
                                                    const float* __restrict__ rho,
                                                    float* __restrict__ lse,
                                                    float* __restrict__ y0)
{
  const int b = blockIdx.y;
  const int m = blockIdx.x*4 + (threadIdx.x>>6);
  const int lane = threadIdx.x & 63;
  const float invrho = 1.0f / fmaxf(rho[0], EPSF);
  float* row = S + (size_t)(b*M_ + m)*N_;
  const float4* row4 = (const float4*)row;
  float4 vals[8];
  float mx = -3.4e38f;
  #pragma unroll
  for (int k=0;k<8;k++){
    float4 v = row4[lane + 64*k];
    vals[k] = v;
    mx = fmaxf(mx, fmaxf(fmaxf(v.x,v.y), fmaxf(v.z,v.w)));
  }
  mx = wredmax(mx);
  float e1=0.0f;
  #pragma unroll
  for (int k=0;k<8;k++){
    float4 v = vals[k];
    e1 += __expf(v.x-mx)+__expf(v.y-mx)+__expf(v.z-mx)+__expf(v.w-mx);
  }
  e1 = wredsum(e1);
  const float l = mx + __logf(e1);
  uint2* rowh2 = (uint2*)row;
  float y2 = 0.0f;
  #pragma unroll
  for (int k=0;k<8;k++){
    float4 v = vals[k];
    unsigned short h0 = f2h(__expf((v.x-l)*invrho));
    unsigned short h1 = f2h(__expf((v.y-l)*invrho));
    unsigned short h2 = f2h(__expf((v.z-l)*invrho));
    unsigned short h3 = f2h(__expf((v.w-l)*invrho));
    y2 += h2f(h0)+h2f(h1)+h2f(h2)+h2f(h3);
    uint2 pk;
    pk.x = (unsigned)h0 | ((unsigned)h1<<16);
    pk.y = (unsigned)h2 | ((unsigned)h3<<16);
    rowh2[lane + 64*k] = pk;
  }
  y2 = wredsum(y2);
  if (lane==0){
    lse[b*M_+m] = l;
    y0 [b*M_+m] = y2;
  }
}

__global__ __launch_bounds__(256) void init_kernel(const float* __restrict__ y0,
                                                   float* __restrict__ u, float* __restrict__ v,
                                                   float* __restrict__ w, float* __restrict__ g)
{
  const int b = blockIdx.x; const int t = threadIdx.x;
  float s = 0.0f;
  for (int i=t;i<M_;i+=256) s += y0[b*M_+i];
  s = wredsum(s);
  __shared__ float red[4];
  __shared__ float gsh;
  if ((t&63)==0) red[t>>6]=s;
  __syncthreads();
  if (t==0){
    float tot = red[0]+red[1]+red[2]+red[3];
    float gg = 1.0f / fmaxf(tot, EPSF);
    g[b]=gg; gsh=gg;
  }
  __syncthreads();
  float gg = gsh;
  for (int i=t;i<M_;i+=256){
    float rs = gg * y0[b*M_+i];
    u[b*M_+i] = fminf(AVAL / fmaxf(rs, EPSF), 1.0f);
    v[b*M_+i] = 1.0f;
    w[b*M_+i] = 0.0f;
  }
}

// ---- col pass (it=0 only): w_j += sum_i u_i K̂_ij over 64-row chunks ----
__global__ __launch_bounds__(256) void col_kernel(const float* __restrict__ S,
                                                  const float* __restrict__ u,
                                                  float* __restrict__ w)
{
  const int b  = blockIdx.y;
  const int i0 = blockIdx.x*64;
  const int t  = threadIdx.x;
  float acc[8];
  #pragma unroll
  for (int k=0;k<8;k++) acc[k]=0.0f;
  for (int i=0;i<64;i++){
    int r = i0+i;
    float ui = u[b*M_+r];
    uint4 su = ((const uint4*)(S + (size_t)(b*M_ + r)*N_))[t];
    acc[0] += ui*h2f((unsigned short)(su.x&0xffff));
    acc[1] += ui*h2f((unsigned short)(su.x>>16));
    acc[2] += ui*h2f((unsigned short)(su.y&0xffff));
    acc[3] += ui*h2f((unsigned short)(su.y>>16));
    acc[4] += ui*h2f((unsigned short)(su.z&0xffff));
    acc[5] += ui*h2f((unsigned short)(su.z>>16));
    acc[6] += ui*h2f((unsigned short)(su.w&0xffff));
    acc[7] += ui*h2f((unsigned short)(su.w>>16));
  }
  #pragma unroll
  for (int k=0;k<8;k++) atomicAdd(&w[b*N_+t*8+k], acc[k]);
}

// ---- fused row+col pass (it>=1): ONE read of K̂ does both
//      u_i *= min(a/max(g u_i (K̂ v)_i,eps),1)   then   w_j += sum_i u_i_new K̂_ij
//      Each warp owns 16 rows; a row's K̂ values stay in registers between the
//      dot (row update) and the column accumulation.  wredsum broadcasts the
//      dot to all lanes, so every lane computes the identical u_new locally. ----
__global__ __launch_bounds__(256) void fused_rc_kernel(const float* __restrict__ S,
                                                       const float* __restrict__ vv,
                                                       float* __restrict__ u,
                                                       float* __restrict__ w,
                                                       const float* __restrict__ g)
{
  __shared__ float wsh[4][2048];
  const int b   = blockIdx.y;
  const int i0  = blockIdx.x*64;
  const int t   = threadIdx.x;
  const int wid = t>>6, lane = t&63;
  const float gg = g[b];
  const float4* vp = (const float4*)(vv + (size_t)b*N_);

  float acc[32];
  #pragma unroll
  for (int k=0;k<32;k++) acc[k]=0.0f;

  for (int r=0;r<16;r++){
    const int m = i0 + wid*16 + r;
    const uint4* rowh = (const uint4*)(S + (size_t)(b*M_ + m)*N_);
    float sv[32];
    float dot = 0.0f;
    #pragma unroll
    for (int k=0;k<4;k++){
      uint4 su  = rowh[lane + 64*k];
      float4 v0 = vp[(lane+64*k)*2];
      float4 v1 = vp[(lane+64*k)*2+1];
      float s0 = h2f((unsigned short)(su.x&0xffff));
      float s1 = h2f((unsigned short)(su.x>>16));
      float s2 = h2f((unsigned short)(su.y&0xffff));
      float s3 = h2f((unsigned short)(su.y>>16));
      float s4 = h2f((unsigned short)(su.z&0xffff));
      float s5 = h2f((unsigned short)(su.z>>16));
      float s6 = h2f((unsigned short)(su.w&0xffff));
      float s7 = h2f((unsigned short)(su.w>>16));
      dot += s0*v0.x + s1*v0.y + s2*v0.z + s3*v0.w
           + s4*v1.x + s5*v1.y + s6*v1.z + s7*v1.w;
      sv[k*8+0]=s0; sv[k*8+1]=s1; sv[k*8+2]=s2; sv[k*8+3]=s3;
      sv[k*8+4]=s4; sv[k*8+5]=s5; sv[k*8+6]=s6; sv[k*8+7]=s7;
    }
    dot = wredsum(dot);
    float ui = u[b*M_+m];
    float rs = gg*ui*dot;
    float un = ui * fminf(AVAL / fmaxf(rs, EPSF), 1.0f);
    if (lane==0) u[b*M_+m] = un;
    #pragma unroll
    for (int k=0;k<32;k++) acc[k] += un * sv[k];
  }

  // per-warp partials -> LDS, combine across the 4 warps, one atomic per col
  #pragma unroll
  for (int k=0;k<4;k++){
    #pragma unroll
    for (int e=0;e<8;e++)
      wsh[wid][(lane+64*k)*8+e] = acc[k*8+e];
  }
  __syncthreads();
  #pragma unroll
  for (int e=0;e<8;e++){
    int j = t*8+e;
    float s = wsh[0][j]+wsh[1][j]+wsh[2][j]+wsh[3][j];
    atomicAdd(&w[b*N_+j], s);
  }
}

__global__ __launch_bounds__(256) void vupd_kernel(float* __restrict__ w,
                                                   float* __restrict__ v,
                                                   float* __restrict__ g)
{
  const int b = blockIdx.x; const int t = threadIdx.x;
  const float gg = g[b];
  float part = 0.0f;
  for (int i=t;i<N_;i+=256){
    float wj = w[b*N_+i];
    float vj = v[b*N_+i];
    float c  = fminf(AVAL/fmaxf(gg*vj*wj,EPSF), 1.0f);
    vj *= c;
    v[b*N_+i]=vj;
    part += wj*vj;
    w[b*N_+i]=0.0f;
  }
  part = wredsum(part);
  __shared__ float red[4];
  if ((t&63)==0) red[t>>6]=part;
  __syncthreads();
  if (t==0){
    float tot = gg*(red[0]+red[1]+red[2]+red[3]);
    g[b] = gg / fmaxf(tot, EPSF);
  }
}

// ---- final: matches fp32 overwrite rows in place; fused rowsum + matches@t^T ----
__global__ __launch_bounds__(256) void final_kernel(float* __restrict__ S,
                                                    const float* __restrict__ u,
                                                    const float* __restrict__ v,
                                                    const float* __restrict__ g,
                                                    const float* __restrict__ tgt,
                                                    float* __restrict__ rowsum,
                                                    float* __restrict__ wref)
{
  const int b = blockIdx.y;
  const int m = blockIdx.x*4 + (threadIdx.x>>6);
  const int lane = threadIdx.x & 63;
  const float gu = g[b]*u[b*M_+m];
  float* row = S + (size_t)(b*M_ + m)*N_;
  const uint4* rowh = (const uint4*)row;
  uint4 su[4];
  #pragma unroll
  for (int k=0;k<4;k++) su[k] = rowh[lane + 64*k];
  __builtin_amdgcn_s_waitcnt(0);
  float4* rowf = (float4*)row;
  const float4* vp = (const float4*)(v + (size_t)b*N_);
  const float4* t0 = (const float4*)(tgt + ((size_t)b*3+0)*N_);
  const float4* t1 = (const float4*)(tgt + ((size_t)b*3+1)*N_);
  const float4* t2 = (const float4*)(tgt + ((size_t)b*3+2)*N_);
  float rs=0.0f, a0=0.0f, a1=0.0f, a2=0.0f;
  #pragma unroll
  for (int k=0;k<4;k++){
    float s[8] = {h2f((unsigned short)(su[k].x&0xffff)), h2f((unsigned short)(su[k].x>>16)),
                  h2f((unsigned short)(su[k].y&0xffff)), h2f((unsigned short)(su[k].y>>16)),
                  h2f((unsigned short)(su[k].z&0xffff)), h2f((unsigned short)(su[k].z>>16)),
                  h2f((unsigned short)(su[k].w&0xffff)), h2f((unsigned short)(su[k].w>>16))};
    int i2 = (lane+64*k)*2;
    #pragma unroll
    for (int h=0;h<2;h++){
      float4 v4 = vp[i2+h];
      float4 q0 = t0[i2+h], q1 = t1[i2+h], q2 = t2[i2+h];
      float m0 = gu*s[h*4+0]*v4.x;
      float m1 = gu*s[h*4+1]*v4.y;
      float m2 = gu*s[h*4+2]*v4.z;
      float m3 = gu*s[h*4+3]*v4.w;
      rs += m0+m1+m2+m3;
      a0 += m0*q0.x + m1*q0.y + m2*q0.z + m3*q0.w;
      a1 += m0*q1.x + m1*q1.y + m2*q1.z + m3*q1.w;
      a2 += m0*q2.x + m1*q2.y + m2*q2.z + m3*q2.w;
      rowf[i2+h] = make_float4(m0,m1,m2,m3);
    }
  }
  rs = wredsum(rs); a0=wredsum(a0); a1=wredsum(a1); a2=wredsum(a2);
  if (lane==0){
    rowsum[b*M_+m] = rs;
    float inv = 1.0f/(rs+1e-6f);
    size_t o = ((size_t)b*M_+m)*3;
    wref[o]=a0*inv; wref[o+1]=a1*inv; wref[o+2]=a2*inv;
  }
}

// ---------------- 3x3 Kabsch via Jacobi on cov^T cov (verified R1) ----------------
__device__ __forceinline__ void mat3_svd_rot(const float cov[3][3], float R[3][3])
{
  float mx = 1e-30f;
  for (int p=0;p<3;p++) for (int q=0;q<3;q++) mx = fmaxf(mx, fabsf(cov[p][q]));
  const float inv = 1.0f/mx;
  float Cm[3][3];
  for (int p=0;p<3;p++) for (int q=0;q<3;q++) Cm[p][q]=cov[p][q]*inv;
  float G[3][3];
  for (int p=0;p<3;p++)
    for (int q=0;q<3;q++)
      G[p][q] = Cm[0][p]*Cm[0][q] + Cm[1][p]*Cm[1][q] + Cm[2][p]*Cm[2][q];
  float V[3][3] = {{1,0,0},{0,1,0},{0,0,1}};
  const int PP[3]={0,0,1}, QQ[3]={1,2,2};
  for (int sweep=0;sweep<12;sweep++){
    for (int r=0;r<3;r++){
      int p=PP[r], q=QQ[r];
      float apq = G[p][q];
      if (fabsf(apq) < 1e-20f) continue;
      float tau = (G[q][q]-G[p][p])/(2.0f*apq);
      float tt  = (tau>=0.0f?1.0f:-1.0f)/(fabsf(tau)+sqrtf(1.0f+tau*tau));
      float cc  = 1.0f/sqrtf(1.0f+tt*tt);
      float ss  = tt*cc;
      for (int k=0;k<3;k++){ float gkp=G[k][p], gkq=G[k][q]; G[k][p]=cc*gkp-ss*gkq; G[k][q]=ss*gkp+cc*gkq; }
      for (int k=0;k<3;k++){ float gpk=G[p][k], gqk=G[q][k]; G[p][k]=cc*gpk-ss*gqk; G[q][k]=ss*gpk+cc*gqk; }
      for (int k=0;k<3;k++){ float vkp=V[k][p], vkq=V[k][q]; V[k][p]=cc*vkp-ss*vkq; V[k][q]=ss*vkp+cc*vkq; }
    }
  }
  float ev[3]={G[0][0],G[1][1],G[2][2]};
  int i0=0,i1=1,i2=2,tmp;
  if (ev[i0]<ev[i1]){tmp=i0;i0=i1;i1=tmp;}
  if (ev[i0]<ev[i2]){tmp=i0;i0=i2;i2=tmp;}
  if (ev[i1]<ev[i2]){tmp=i1;i1=i2;i2=tmp;}
  const int idx[3]={i0,i1,i2};
  float Vs[3][3];
  for (int k=0;k<3;k++) for (int i=0;i<3;i++) Vs[i][k]=V[i][idx[k]];
  float U[3][3]; float nrm[3];
  for (int k=0;k<3;k++){
    float ux = Cm[0][0]*Vs[0][k]+Cm[0][1]*Vs[1][k]+Cm[0][2]*Vs[2][k];
    float uy = Cm[1][0]*Vs[0][k]+Cm[1][1]*Vs[1][k]+Cm[1][2]*Vs[2][k];
    float uz = Cm[2][0]*Vs[0][k]+Cm[2][1]*Vs[1][k]+Cm[2][2]*Vs[2][k];
    float n = sqrtf(ux*ux+uy*uy+uz*uz);
    nrm[k]=n;
    float in = (n>1e-20f)?1.0f/n:0.0f;
    U[0][k]=ux*in; U[1][k]=uy*in; U[2][k]=uz*in;
  }
  if (nrm[2] < 1e-6f*fmaxf(nrm[0],1e-20f)){
    U[0][2]=U[1][0]*U[2][1]-U[2][0]*U[1][1];
    U[1][2]=U[2][0]*U[0][1]-U[0][0]*U[2][1];
    U[2][2]=U[0][0]*U[1][1]-U[1][0]*U[0][1];
  }
  float detC = Cm[0][0]*(Cm[1][1]*Cm[2][2]-Cm[1][2]*Cm[2][1])
             - Cm[0][1]*(Cm[1][0]*Cm[2][2]-Cm[1][2]*Cm[2][0])
             + Cm[0][2]*(Cm[1][0]*Cm[2][1]-Cm[1][1]*Cm[2][0]);
  float d2 = (detC>0.0f)?1.0f:-1.0f;
  for (int p=0;p<3;p++)
    for (int q=0;q<3;q++)
      R[p][q] = Vs[p][0]*U[q][0] + Vs[p][1]*U[q][1] + d2*Vs[p][2]*U[q][2];
}

__global__ __launch_bounds__(256) void rigid_kernel(const float* __restrict__ src,
                                                    const float* __restrict__ wref,
                                                    const float* __restrict__ rowsum,
                                                    float* __restrict__ out)
{
  const int b = blockIdx.x; const int t = threadIdx.x;
  float acc[16];
  #pragma unroll
  for (int k=0;k<16;k++) acc[k]=0.0f;
  for (int i=t;i<M_;i+=256){
    float wgt = rowsum[b*M_+i];
    float ax = src[((size_t)b*3+0)*M_+i];
    float ay = src[((size_t)b*3+1)*M_+i];
    float az = src[((size_t)b*3+2)*M_+i];
    const float* wr = wref + ((size_t)b*M_+i)*3;
    float bx=wr[0], by=wr[1], bz=wr[2];
    acc[0]+=wgt;
    acc[1]+=wgt*ax; acc[2]+=wgt*ay; acc[3]+=wgt*az;
    acc[4]+=wgt*bx; acc[5]+=wgt*by; acc[6]+=wgt*bz;
    acc[7] +=wgt*ax*bx; acc[8] +=wgt*ax*by; acc[9] +=wgt*ax*bz;
    acc[10]+=wgt*ay*bx; acc[11]+=wgt*ay*by; acc[12]+=wgt*ay*bz;
    acc[13]+=wgt*az*bx; acc[14]+=wgt*az*by; acc[15]+=wgt*az*bz;
  }
  __shared__ float red[4][16];
  const int wid = t>>6, lane = t&63;
  #pragma unroll
  for (int k=0;k<16;k++){
    float v = acc[k];
    #pragma unroll
    for (int off=32; off; off>>=1) v += __shfl_xor(v, off);
    if (lane==0) red[wid][k]=v;
  }
  __syncthreads();
  if (t==0){
    float s[16];
    #pragma unroll
    for (int k=0;k<16;k++) s[k]=red[0][k]+red[1][k]+red[2][k]+red[3][k];
    float wsum = s[0];
    float denom = wsum + 1e-6f;
    float ca[3]={s[1]/denom, s[2]/denom, s[3]/denom};
    float cb[3]={s[4]/denom, s[5]/denom, s[6]/denom};
    float sw = wsum/denom;
    float cov[3][3];
    for (int p=0;p<3;p++)
      for (int q=0;q<3;q++)
        cov[p][q] = s[7+p*3+q]/denom + (sw-2.0f)*ca[p]*cb[q];
    float R[3][3];
    mat3_svd_rot(cov, R);
    float tr[3];
    for (int p=0;p<3;p++)
      tr[p] = -(R[p][0]*ca[0]+R[p][1]*ca[1]+R[p][2]*ca[2]) + cb[p];
    for (int p=0;p<3;p++)
      for (int q=0;q<3;q++)
        out[b*9 + p*3 + q] = R[p][q];
    for (int p=0;p<3;p++)
      out[144 + b*3 + p] = tr[p];
  }
}

extern "C" void kernel_launch(void* const* d_in, const int* in_sizes, int n_in,
                              void* d_out, int out_size, void* d_ws, size_t ws_size,
                              hipStream_t stream)
{
  const float* se  = (const float*)d_in[0];
  const float* te  = (const float*)d_in[1];
  const float* src = (const float*)d_in[2];
  const float* tgt = (const float*)d_in[3];
  const float* rho = (const float*)d_in[4];
  float* out = (float*)d_out;
  float* S   = out + 192;                 // matches region doubles as S / K̂ scratch
  float* ws  = (float*)d_ws;
  float* lse = ws;                        // 16*2048
  float* y0  = ws + 32768;                // 16*2048 (also final rowsum)
  float* u   = ws + 65536;
  float* v   = ws + 98304;
  float* w   = ws + 131072;
  float* g   = ws + 163840;               // 16
  float* wref= ws + 163904;               // 16*2048*3 -> ends at float 262208 (byte 1048832)

  // split-bf16 operand planes (behind the existing ws layout)
  const size_t PLANE_G     = (size_t)16*32*2048;          // granules per plane
  const size_t PLANE_BYTES = PLANE_G*16;                  // 16.78 MB
  const size_t PLANE_OFF   = 1048832;                     // 16B-aligned
  const size_t need        = PLANE_OFF + 4*PLANE_BYTES;   // ~68.2 MB

  if (ws_size >= need){
    uint4* Ah = (uint4*)((char*)d_ws + PLANE_OFF);
    uint4* Al = Ah + PLANE_G;
    uint4* Bh = Al + PLANE_G;
    uint4* Bl = Bh + PLANE_G;
    convert_kernel<<<dim3(8,32,32),256,0,stream>>>(se,te,Ah,Al,Bh,Bl);
    gemm_fast     <<<dim3(16,16,16),256,0,stream>>>(Ah,Al,Bh,Bl,S);
  } else {
    gemm_kernel   <<<dim3(16,16,16),256,0,stream>>>(se,te,S);
  }
  stats_kernel<<<dim3(512,16),  256,0,stream>>>(S,rho,lse,y0);
  init_kernel <<<dim3(16),      256,0,stream>>>(y0,u,v,w,g);
  // it=0: col only (init already applied the first row update)
  col_kernel <<<dim3(32,16),256,0,stream>>>(S,u,w);
  vupd_kernel<<<dim3(16),   256,0,stream>>>(w,v,g);
  // it=1..4: fused row+col — one K̂ read per iteration instead of two
  for (int it=1; it<5; ++it){
    fused_rc_kernel<<<dim3(32,16),256,0,stream>>>(S,v,u,w,g);
    vupd_kernel    <<<dim3(16),   256,0,stream>>>(w,v,g);
  }
  final_kernel<<<dim3(512,16),256,0,stream>>>(S,u,v,g,tgt,y0,wref);
  rigid_kernel<<<dim3(16),    256,0,stream>>>(src,wref,y0,out);
}